// Round 1
// baseline (223.636 us; speedup 1.0000x reference)
//
#include <hip/hip_runtime.h>

#define EPS 1e-8f
#define LN_EPS 1e-5f
#define NROWS 8192
#define SLEN 4096
#define PROBS_OFF 2097152   // 8192*256

typedef __attribute__((ext_vector_type(8))) short bf16x8;
typedef __attribute__((ext_vector_type(4))) float f32x4;

__device__ __forceinline__ short f2bf(float f) {
    unsigned u = __float_as_uint(f);
    unsigned r = (u + 0x7FFFu + ((u >> 16) & 1u)) >> 16;  // RNE, no NaN inputs here
    return (short)r;
}

// ---------------- K1: per-row features (HBM-bound) ----------------
__global__ __launch_bounds__(256) void k_features(const float* __restrict__ prices,
                                                  float* __restrict__ out) {
    __shared__ float s[SLEN];
    __shared__ float red[12];
    const int b = blockIdx.x;
    const int t = threadIdx.x;
    const float* rowp = prices + (size_t)b * SLEN;

    // coalesced row load -> LDS
    #pragma unroll
    for (int i = 0; i < 4; ++i) {
        int idx = (i * 256 + t) * 4;
        float4 v = *(const float4*)(rowp + idx);
        *(float4*)(s + idx) = v;
    }
    __syncthreads();

    // thread handles positions [16t, 16t+16); prev[] = s[p0-20 .. p0), zero-padded
    const int p0 = t * 16;
    float seg[16], prev[20];
    #pragma unroll
    for (int i = 0; i < 4; ++i)
        *(float4*)(seg + 4*i) = *(const float4*)(s + p0 + 4*i);
    #pragma unroll
    for (int i = 0; i < 5; ++i) {
        int base = p0 - 20 + 4*i;
        float4 pv;
        if (base >= 0) pv = *(const float4*)(s + base);
        else pv = make_float4(0.f, 0.f, 0.f, 0.f);
        *(float4*)(prev + 4*i) = pv;
    }

    // rolling window sum W(p) = sum s[max(0,p-19)..p]; zeros in prev make edges branch-free
    float W = seg[0];
    #pragma unroll
    for (int j = 1; j < 20; ++j) W += prev[j];

    float x = seg[0];
    float sum = x, sq = x * x;
    float cnt = fminf((float)(p0 + 1), 20.0f);
    float sma = W * __builtin_amdgcn_rcpf(cnt);
    float ts = (x - sma) * __builtin_amdgcn_rcpf(sma + EPS);
    #pragma unroll
    for (int j = 1; j < 16; ++j) {
        x = seg[j];
        W += x - prev[j];                 // prev[j] == s[p0+j-20] (0 if <0)
        sum += x;
        sq = fmaf(x, x, sq);
        float c2 = fminf((float)(p0 + j + 1), 20.0f);
        float sm = W * __builtin_amdgcn_rcpf(c2);
        ts += (x - sm) * __builtin_amdgcn_rcpf(sm + EPS);
    }

    #pragma unroll
    for (int off = 32; off > 0; off >>= 1) {
        sum += __shfl_xor(sum, off);
        sq  += __shfl_xor(sq,  off);
        ts  += __shfl_xor(ts,  off);
    }
    const int wv = t >> 6, lane = t & 63;
    if (lane == 0) { red[wv*3] = sum; red[wv*3+1] = sq; red[wv*3+2] = ts; }
    __syncthreads();

    if (t == 0) {
        float S = red[0] + red[3] + red[6] + red[9];
        float Q = red[1] + red[4] + red[7] + red[10];
        float T = red[2] + red[5] + red[8] + red[11];
        float mean = S * (1.0f / 4096.0f);
        float var  = fmaxf((Q - 4096.0f * mean * mean) * (1.0f / 4095.0f), 0.0f);
        float p_last = s[SLEN - 1];
        float p_m10  = s[SLEN - 10];
        float4 c;
        c.x = T * (1.0f / 4096.0f);            // f_trend
        c.y = (p_last - p_m10) / (p_m10 + EPS); // f_mom
        c.z = (p_last - mean) / (mean + EPS);   // f_mr
        c.w = sqrtf(var) / (mean + EPS);        // f_cyc
        // stage combined[b] in the rf slot; K2 reads it before overwriting
        *(float4*)(out + (size_t)b * 256) = c;
    }
}

// ---------------- K2: encoder + LN + head (MFMA) + softmax ----------------
#define ROWS 32

__global__ __launch_bounds__(256) void k_head(
    float* __restrict__ out,
    const float* __restrict__ enc_w, const float* __restrict__ enc_b,
    const float* __restrict__ enc_g, const float* __restrict__ enc_bt,
    const float* __restrict__ w1, const float* __restrict__ b1,
    const float* __restrict__ w2, const float* __restrict__ b2)
{
    __shared__ float comb[ROWS][4];
    __shared__ short rfb[ROWS][264];   // bf16 rf tile, +8 pad (16B-aligned rows)
    __shared__ float hbuf[ROWS][68];   // padded to break 4-way bank conflicts

    const int t = threadIdx.x;
    const int r0 = blockIdx.x * ROWS;
    const int lane = t & 63, wave = t >> 6;
    const int l15 = lane & 15, q = lane >> 4;

    // phase 0: read combined (written by K1 into rf slots of OUR rows)
    if (t < ROWS * 4)
        comb[t >> 2][t & 3] = out[(size_t)(r0 + (t >> 2)) * 256 + (t & 3)];

    // B-frags: wave w owns n-tile w (cols [16w,16w+16)); whole K=256 in 32 VGPRs.
    // B layout: n = lane&15, k = (lane>>4)*8 + j  (per k-tile of 32)
    bf16x8 bfrag[8];
    #pragma unroll
    for (int kt = 0; kt < 8; ++kt) {
        #pragma unroll
        for (int j = 0; j < 8; ++j) {
            int k = kt * 32 + q * 8 + j;
            bfrag[kt][j] = f2bf(w1[k * 64 + wave * 16 + l15]);
        }
    }

    // encoder weights for this thread's (e=wave, o=lane)
    const float ew0 = enc_w[wave * 256 + lane];
    const float ew1v = enc_w[wave * 256 + 64 + lane];
    const float ew2v = enc_w[wave * 256 + 128 + lane];
    const float ew3v = enc_w[wave * 256 + 192 + lane];
    const float ebv = enc_b[t], egv = enc_g[t], btv = enc_bt[t];

    __syncthreads();

    // phase 1: encoder + relu + LayerNorm (one wave == one e-group of 64)
    for (int r = 0; r < ROWS; ++r) {
        float4 cb = *(const float4*)comb[r];
        float v = fmaf(cb.x, ew0, fmaf(cb.y, ew1v, fmaf(cb.z, ew2v, fmaf(cb.w, ew3v, ebv))));
        v = fmaxf(v, 0.0f);
        float sm = v;
        #pragma unroll
        for (int off = 32; off > 0; off >>= 1) sm += __shfl_xor(sm, off);
        float mu = sm * (1.0f / 64.0f);
        float d = v - mu;
        float vs = d * d;
        #pragma unroll
        for (int off = 32; off > 0; off >>= 1) vs += __shfl_xor(vs, off);
        float y = fmaf(d * rsqrtf(vs * (1.0f / 64.0f) + LN_EPS), egv, btv);
        out[(size_t)(r0 + r) * 256 + t] = y;       // regime_features (fp32, exact)
        rfb[r][t] = f2bf(y);                       // bf16 copy for MFMA head
    }
    __syncthreads();

    // phase 2: h = rf @ w1 via 16x16x32 bf16 MFMA; wave does m-tiles {0,1} for its n-tile
    f32x4 acc0 = {0.f, 0.f, 0.f, 0.f}, acc1 = {0.f, 0.f, 0.f, 0.f};
    #pragma unroll
    for (int kt = 0; kt < 8; ++kt) {
        bf16x8 a0 = *(const bf16x8*)&rfb[l15][kt * 32 + q * 8];
        bf16x8 a1 = *(const bf16x8*)&rfb[16 + l15][kt * 32 + q * 8];
        acc0 = __builtin_amdgcn_mfma_f32_16x16x32_bf16(a0, bfrag[kt], acc0, 0, 0, 0);
        acc1 = __builtin_amdgcn_mfma_f32_16x16x32_bf16(a1, bfrag[kt], acc1, 0, 0, 0);
    }

    // epilogue: C layout col=lane&15, row=(lane>>4)*4+reg
    const int col = wave * 16 + l15;
    const float b1v = b1[col];
    #pragma unroll
    for (int rg = 0; rg < 4; ++rg) {
        hbuf[q * 4 + rg][col]      = fmaxf(acc0[rg] + b1v, 0.0f);
        hbuf[16 + q * 4 + rg][col] = fmaxf(acc1[rg] + b1v, 0.0f);
    }
    __syncthreads();

    // phase 3: logits = h @ w2 + b2, softmax over 4 within lane-quads
    if (t < 128) {
        int r = t >> 2, c = t & 3;
        float lg = b2[c];
        #pragma unroll
        for (int j = 0; j < 64; ++j) lg = fmaf(hbuf[r][j], w2[j * 4 + c], lg);
        float mx = fmaxf(lg, __shfl_xor(lg, 1, 4));
        mx = fmaxf(mx, __shfl_xor(mx, 2, 4));
        float ex = __expf(lg - mx);
        float s2 = ex + __shfl_xor(ex, 1, 4);
        s2 += __shfl_xor(s2, 2, 4);
        out[PROBS_OFF + (size_t)(r0 + r) * 4 + c] = ex / s2;
    }
}

extern "C" void kernel_launch(void* const* d_in, const int* in_sizes, int n_in,
                              void* d_out, int out_size, void* d_ws, size_t ws_size,
                              hipStream_t stream) {
    const float* prices  = (const float*)d_in[0];
    const float* enc_w   = (const float*)d_in[1];
    const float* enc_b   = (const float*)d_in[2];
    const float* enc_g   = (const float*)d_in[3];
    const float* enc_bt  = (const float*)d_in[4];
    const float* head_w1 = (const float*)d_in[5];
    const float* head_b1 = (const float*)d_in[6];
    const float* head_w2 = (const float*)d_in[7];
    const float* head_b2 = (const float*)d_in[8];
    float* out = (float*)d_out;

    k_features<<<NROWS, 256, 0, stream>>>(prices, out);
    k_head<<<NROWS / ROWS, 256, 0, stream>>>(out, enc_w, enc_b, enc_g, enc_bt,
                                             head_w1, head_b1, head_w2, head_b2);
}